// Round 1
// baseline (1684.665 us; speedup 1.0000x reference)
//
#include <hip/hip_runtime.h>
#include <hip/hip_bf16.h>

// StabilityPredictorSchnet: B=4, L=384, H=128, F=384
// Fused CFConv (edge-MLP + neighbor contraction) + head MLP + masked mean.
//
// Strategy: one block per (b,l). Loop over 6 k-tiles of 64 edge rows:
//   GEMM1: [64x128] @ fw1T -> gelu -> sT1 (bf16, LDS)   (MFMA 16x16x32 bf16)
//   GEMM2: sT1 [64x384] @ fw2T -> gelu -> * h_V -> xc[] (register accum)
// Then head MLP (fp32, tiny) and atomicAdd into per-batch accumulator.

#define Bz 4
#define Lz 384
#define Hz 128
#define Fz 384

typedef short bf16x8 __attribute__((ext_vector_type(8)));
typedef float f32x4 __attribute__((ext_vector_type(4)));

__device__ __forceinline__ unsigned short f2bf(float f) {
  unsigned int u = __float_as_uint(f);
  u += 0x7FFFu + ((u >> 16) & 1u);   // RNE bf16
  return (unsigned short)(u >> 16);
}

__device__ __forceinline__ float gelu_f(float x) {
  return 0.5f * x * (1.0f + erff(x * 0.70710678118654752f));
}

// ---- prep: zero accumulators; fw1/fw2 -> bf16, transposed to [n][k] ----
__global__ __launch_bounds__(256) void prep_kernel(
    const float* __restrict__ fw1, const float* __restrict__ fw2,
    unsigned short* __restrict__ fw1T, unsigned short* __restrict__ fw2T,
    float* __restrict__ accbuf)
{
  int tid = blockIdx.x * 256 + threadIdx.x;
  if (tid < 16) accbuf[tid] = 0.0f;
  if (tid < Hz * Fz) {                 // fw1T[n*128+k] = fw1[k*384+n]
    int n = tid >> 7;
    int k = tid & 127;
    fw1T[tid] = f2bf(fw1[k * Fz + n]);
  }
  if (tid < Fz * Fz) {                 // fw2T[n*384+k] = fw2[k*384+n]
    int n = tid / Fz;
    int k = tid - n * Fz;
    fw2T[tid] = f2bf(fw2[k * Fz + n]);
  }
}

__global__ __launch_bounds__(256) void schnet_main(
    const float* __restrict__ hV, const float* __restrict__ hE,
    const float* __restrict__ mask,
    const unsigned short* __restrict__ fw1T, const float* __restrict__ fb1,
    const unsigned short* __restrict__ fw2T, const float* __restrict__ fb2,
    const float* __restrict__ hw1, const float* __restrict__ hb1,
    const float* __restrict__ hw2, const float* __restrict__ hb2,
    const float* __restrict__ hw3, const float* __restrict__ hb3,
    float* __restrict__ accbuf)
{
  const int bl   = blockIdx.x;
  const int b    = bl / Lz;
  const int l    = bl - b * Lz;
  const int tid  = threadIdx.x;
  const int wave = tid >> 6;
  const int lane = tid & 63;
  const int lr   = lane & 15;   // 16-index (row for A, col for B/C)
  const int quad = lane >> 4;   // 0..3
  const int n_base = wave * 96; // each wave owns 96 of 384 output features

  // sT1 row stride 392 shorts = 784B = 196 dwords; 196%32=4 -> b128 reads are
  // a free 2-way bank conflict (m136).
  __shared__ unsigned short sT1[64][392];
  __shared__ float sXC[Fz];
  __shared__ float sHp[2][Hz];
  __shared__ float sH1[Hz];
  __shared__ float sH2[64];

  const float* hE_bl = hE + (size_t)bl * (Lz * Hz);

  float xc[6] = {0.f, 0.f, 0.f, 0.f, 0.f, 0.f};
  const f32x4 zero4 = {0.f, 0.f, 0.f, 0.f};

  for (int it = 0; it < 6; ++it) {
    // ================= GEMM1: [64x128] @ fw1T -> acc =================
    f32x4 acc[4][6];
    #pragma unroll
    for (int mt = 0; mt < 4; ++mt)
      #pragma unroll
      for (int nt = 0; nt < 6; ++nt)
        acc[mt][nt] = zero4;

    #pragma unroll
    for (int ks = 0; ks < 4; ++ks) {
      const int k0 = ks * 32 + quad * 8;
      bf16x8 afr[4];
      #pragma unroll
      for (int mt = 0; mt < 4; ++mt) {
        const float* src = hE_bl + (size_t)(it * 64 + mt * 16 + lr) * Hz + k0;
        float4 lo = *(const float4*)(src);
        float4 hi = *(const float4*)(src + 4);
        union { bf16x8 v; unsigned short u[8]; } p;
        p.u[0] = f2bf(lo.x); p.u[1] = f2bf(lo.y);
        p.u[2] = f2bf(lo.z); p.u[3] = f2bf(lo.w);
        p.u[4] = f2bf(hi.x); p.u[5] = f2bf(hi.y);
        p.u[6] = f2bf(hi.z); p.u[7] = f2bf(hi.w);
        afr[mt] = p.v;
      }
      bf16x8 bfr[6];
      #pragma unroll
      for (int nt = 0; nt < 6; ++nt)
        bfr[nt] = *(const bf16x8*)(fw1T + (n_base + nt * 16 + lr) * Hz + k0);
      #pragma unroll
      for (int mt = 0; mt < 4; ++mt)
        #pragma unroll
        for (int nt = 0; nt < 6; ++nt)
          acc[mt][nt] = __builtin_amdgcn_mfma_f32_16x16x32_bf16(
              afr[mt], bfr[nt], acc[mt][nt], 0, 0, 0);
    }

    // WAR guard: previous iteration's GEMM2 must be done reading sT1
    __syncthreads();

    // epilogue 1: bias + gelu -> sT1 (bf16). C/D: row=quad*4+r, col=lr (m89).
    #pragma unroll
    for (int nt = 0; nt < 6; ++nt) {
      const int n = n_base + nt * 16 + lr;
      const float bias = fb1[n];
      #pragma unroll
      for (int mt = 0; mt < 4; ++mt) {
        #pragma unroll
        for (int r = 0; r < 4; ++r) {
          const int m = mt * 16 + quad * 4 + r;
          sT1[m][n] = f2bf(gelu_f(acc[mt][nt][r] + bias));
        }
      }
    }
    __syncthreads();

    // ================= GEMM2: sT1 [64x384] @ fw2T =================
    #pragma unroll
    for (int mt = 0; mt < 4; ++mt)
      #pragma unroll
      for (int nt = 0; nt < 6; ++nt)
        acc[mt][nt] = zero4;

    #pragma unroll
    for (int ks = 0; ks < 12; ++ks) {
      const int k0 = ks * 32 + quad * 8;
      bf16x8 afr[4];
      #pragma unroll
      for (int mt = 0; mt < 4; ++mt)
        afr[mt] = *(const bf16x8*)(&sT1[mt * 16 + lr][k0]);
      bf16x8 bfr[6];
      #pragma unroll
      for (int nt = 0; nt < 6; ++nt)
        bfr[nt] = *(const bf16x8*)(fw2T + (n_base + nt * 16 + lr) * Fz + k0);
      #pragma unroll
      for (int mt = 0; mt < 4; ++mt)
        #pragma unroll
        for (int nt = 0; nt < 6; ++nt)
          acc[mt][nt] = __builtin_amdgcn_mfma_f32_16x16x32_bf16(
              afr[mt], bfr[nt], acc[mt][nt], 0, 0, 0);
    }

    // epilogue 2: bias + gelu, multiply by h_V[b,k,:], accumulate per-column
    #pragma unroll
    for (int nt = 0; nt < 6; ++nt) {
      const int n = n_base + nt * 16 + lr;
      const float bias = fb2[n];
      float part = 0.f;
      #pragma unroll
      for (int mt = 0; mt < 4; ++mt) {
        const float* hv =
            hV + ((size_t)b * Lz + it * 64 + mt * 16 + quad * 4) * Fz + n;
        #pragma unroll
        for (int r = 0; r < 4; ++r) {
          float w = gelu_f(acc[mt][nt][r] + bias);
          part += w * hv[(size_t)r * Fz];
        }
      }
      xc[nt] += part;
    }
  }

  // reduce xc across quads (rows) -> sXC
  #pragma unroll
  for (int nt = 0; nt < 6; ++nt) {
    float v = xc[nt];
    v += __shfl_xor(v, 16);
    v += __shfl_xor(v, 32);
    if (quad == 0) sXC[n_base + nt * 16 + lr] = v;
  }
  __syncthreads();

  // ---- head MLP (fp32, tiny) ----
  {
    int i = tid & 127;
    int half = tid >> 7;
    float a = 0.f;
    const int f0 = half * 192;
    for (int f = f0; f < f0 + 192; ++f) a += sXC[f] * hw1[f * Hz + i];
    sHp[half][i] = a;
  }
  __syncthreads();
  if (tid < Hz) sH1[tid] = gelu_f(sHp[0][tid] + sHp[1][tid] + hb1[tid]);
  __syncthreads();
  if (tid < 64) {
    float a = hb2[tid];
    for (int i = 0; i < Hz; ++i) a += sH1[i] * hw2[i * 64 + tid];
    sH2[tid] = gelu_f(a);
  }
  __syncthreads();
  if (wave == 0) {
    float v = sH2[lane] * hw3[lane];
    #pragma unroll
    for (int off = 32; off >= 1; off >>= 1) v += __shfl_xor(v, off);
    if (lane == 0) {
      float pred = v + hb3[0];
      atomicAdd(&accbuf[b], pred * mask[b * Lz + l]);
    }
  }
}

__global__ __launch_bounds__(64) void finalize_kernel(
    const float* __restrict__ mask, const float* __restrict__ accbuf,
    float* __restrict__ out)
{
  int b = blockIdx.x;
  int lane = threadIdx.x;
  float s = 0.f;
  for (int i = lane; i < Lz; i += 64) s += mask[b * Lz + i];
  #pragma unroll
  for (int off = 32; off >= 1; off >>= 1) s += __shfl_xor(s, off);
  if (lane == 0) {
    float vl = s < 1.0f ? 1.0f : s;
    out[b] = accbuf[b] / sqrtf(vl);
  }
}

extern "C" void kernel_launch(void* const* d_in, const int* in_sizes, int n_in,
                              void* d_out, int out_size, void* d_ws, size_t ws_size,
                              hipStream_t stream)
{
  const float* hV   = (const float*)d_in[0];
  const float* hE   = (const float*)d_in[1];
  const float* mask = (const float*)d_in[2];
  const float* fw1  = (const float*)d_in[3];
  const float* fb1  = (const float*)d_in[4];
  const float* fw2  = (const float*)d_in[5];
  const float* fb2  = (const float*)d_in[6];
  const float* hw1  = (const float*)d_in[7];
  const float* hb1  = (const float*)d_in[8];
  const float* hw2  = (const float*)d_in[9];
  const float* hb2  = (const float*)d_in[10];
  const float* hw3  = (const float*)d_in[11];
  const float* hb3  = (const float*)d_in[12];
  float* out = (float*)d_out;

  // ws layout: [0,64)=acc floats; [1024, +96KB)=fw1T bf16; then fw2T bf16.
  float* accbuf = (float*)d_ws;
  unsigned short* fw1T = (unsigned short*)((char*)d_ws + 1024);
  unsigned short* fw2T = fw1T + Hz * Fz;

  prep_kernel<<<576, 256, 0, stream>>>(fw1, fw2, fw1T, fw2T, accbuf);
  schnet_main<<<Bz * Lz, 256, 0, stream>>>(hV, hE, mask, fw1T, fb1, fw2T, fb2,
                                           hw1, hb1, hw2, hb2, hw3, hb3, accbuf);
  finalize_kernel<<<Bz, 64, 0, stream>>>(mask, accbuf, out);
}

// Round 2
// 1300.227 us; speedup vs baseline: 1.2957x; 1.2957x over previous
//
#include <hip/hip_runtime.h>
#include <hip/hip_bf16.h>

// StabilityPredictorSchnet: B=4, L=384, H=128, F=384
// One block per (b,l). 12 k-tiles of 32 edge rows, software-pipelined:
//   stage h_E tile -> LDS bf16 (once per block, prefetched in registers)
//   GEMM1: sA[32x128] @ fw1T -> gelu -> sT1 (bf16 LDS)  [mfma 16x16x32 bf16]
//   GEMM2: sT1[32x384] @ fw2T -> gelu -> * h_V -> xc[]  (register accum)
// Then head MLP (fp32) + atomicAdd per batch; tiny finalize kernel.
// Register budget: chunked acc[2][6] (48 VGPR) + launch_bounds(256,4)
// => <=128 VGPR, 4 blocks/CU (LDS 37.1 KB/block). R1 failed on 256-VGPR
// spills (WRITE_SIZE 505 MB of scratch) + 4x redundant h_E loads.

#define Bz 4
#define Lz 384
#define Hz 128
#define Fz 384
#define KT 32          // k-tile rows
#define NIT 12         // 384 / KT

typedef short bf16x8 __attribute__((ext_vector_type(8)));
typedef float f32x4 __attribute__((ext_vector_type(4)));

__device__ __forceinline__ unsigned short f2bf(float f) {
  unsigned int u = __float_as_uint(f);
  u += 0x7FFFu + ((u >> 16) & 1u);   // RNE bf16
  return (unsigned short)(u >> 16);
}

// gelu(x) = 0.5x(1+erf(x/sqrt2)); erf via A&S 7.1.26 (|err|<=1.5e-7), branch-free
__device__ __forceinline__ float gelu_f(float x) {
  const float a1 = 0.254829592f, a2 = -0.284496736f, a3 = 1.421413741f;
  const float a4 = -1.453152027f, a5 = 1.061405429f;
  float z = fabsf(x) * 0.7071067811865476f;
  float t = __builtin_amdgcn_rcpf(__builtin_fmaf(0.3275911f, z, 1.0f));
  float poly = t * (a1 + t * (a2 + t * (a3 + t * (a4 + t * a5))));
  float e = __builtin_fmaf(-poly, __expf(-z * z), 1.0f);
  return 0.5f * x * (1.0f + copysignf(e, x));
}

// ---- prep: zero accumulators; fw1/fw2 -> bf16, transposed to [n][k] ----
__global__ __launch_bounds__(256) void prep_kernel(
    const float* __restrict__ fw1, const float* __restrict__ fw2,
    unsigned short* __restrict__ fw1T, unsigned short* __restrict__ fw2T,
    float* __restrict__ accbuf)
{
  int tid = blockIdx.x * 256 + threadIdx.x;
  if (tid < 16) accbuf[tid] = 0.0f;
  if (tid < Hz * Fz) {                 // fw1T[n*128+k] = fw1[k*384+n]
    int n = tid >> 7;
    int k = tid & 127;
    fw1T[tid] = f2bf(fw1[k * Fz + n]);
  }
  if (tid < Fz * Fz) {                 // fw2T[n*384+k] = fw2[k*384+n]
    int n = tid / Fz;
    int k = tid - n * Fz;
    fw2T[tid] = f2bf(fw2[k * Fz + n]);
  }
}

__global__ __launch_bounds__(256, 4) void schnet_main(
    const float* __restrict__ hV, const float* __restrict__ hE,
    const float* __restrict__ mask,
    const unsigned short* __restrict__ fw1T, const float* __restrict__ fb1,
    const unsigned short* __restrict__ fw2T, const float* __restrict__ fb2,
    const float* __restrict__ hw1, const float* __restrict__ hb1,
    const float* __restrict__ hw2, const float* __restrict__ hb2,
    const float* __restrict__ hw3, const float* __restrict__ hb3,
    float* __restrict__ accbuf)
{
  const int bl   = blockIdx.x;
  const int b    = bl / Lz;
  const int l    = bl - b * Lz;
  const int tid  = threadIdx.x;
  const int wave = tid >> 6;
  const int lane = tid & 63;
  const int lr   = lane & 15;   // 16-index (row for A, col for B/C)
  const int quad = lane >> 4;   // 0..3
  const int n_base = wave * 96; // each wave owns 96 of 384 output features

  // strides in shorts; both are multiples of 8 (16B-aligned ds_read_b128),
  // stride/2 % 32 == 4 -> <=2-way bank aliasing on b128 reads (free, m136)
  __shared__ unsigned short sA[KT][136];   // h_E tile, bf16      (8704 B)
  __shared__ unsigned short sT1[KT][392];  // gelu(hE@fw1) bf16   (25088 B)
  __shared__ float sXC[Fz];
  __shared__ float sHp[2][Hz];
  __shared__ float sH1[Hz];
  __shared__ float sH2[64];

  const float* hE_bl = hE + (size_t)bl * (Lz * Hz);

  float xc[6] = {0.f, 0.f, 0.f, 0.f, 0.f, 0.f};
  const f32x4 zero4 = {0.f, 0.f, 0.f, 0.f};

  // prefetch tile 0 into registers (4 float4 per thread = one 32x128 tile)
  float4 pf[4];
  #pragma unroll
  for (int j = 0; j < 4; ++j)
    pf[j] = *(const float4*)(hE_bl + 4 * (tid + 256 * j));

  for (int it = 0; it < NIT; ++it) {
    // (a) prev GEMM2 done reading sT1, prev GEMM1 done reading sA
    __syncthreads();

    // write prefetched tile -> sA (bf16), then issue next tile's loads
    #pragma unroll
    for (int j = 0; j < 4; ++j) {
      int f = 4 * (tid + 256 * j);       // flat float idx in 32x128 tile
      int row = f >> 7, col = f & 127;
      short4 s;
      s.x = (short)f2bf(pf[j].x); s.y = (short)f2bf(pf[j].y);
      s.z = (short)f2bf(pf[j].z); s.w = (short)f2bf(pf[j].w);
      *(short4*)&sA[row][col] = s;
    }
    if (it + 1 < NIT) {
      const float* src = hE_bl + (size_t)(it + 1) * (KT * Hz);
      #pragma unroll
      for (int j = 0; j < 4; ++j)
        pf[j] = *(const float4*)(src + 4 * (tid + 256 * j));
    }
    // (b) sA ready
    __syncthreads();

    // ================= GEMM1: sA[32x128] @ fw1T -> acc =================
    f32x4 acc[2][6];
    #pragma unroll
    for (int mt = 0; mt < 2; ++mt)
      #pragma unroll
      for (int nt = 0; nt < 6; ++nt)
        acc[mt][nt] = zero4;

    #pragma unroll 2
    for (int ks = 0; ks < 4; ++ks) {
      const int k0 = ks * 32 + quad * 8;
      bf16x8 afr[2];
      #pragma unroll
      for (int mt = 0; mt < 2; ++mt)
        afr[mt] = *(const bf16x8*)(&sA[mt * 16 + lr][k0]);
      bf16x8 bfr[6];
      #pragma unroll
      for (int nt = 0; nt < 6; ++nt)
        bfr[nt] = *(const bf16x8*)(fw1T + (n_base + nt * 16 + lr) * Hz + k0);
      #pragma unroll
      for (int mt = 0; mt < 2; ++mt)
        #pragma unroll
        for (int nt = 0; nt < 6; ++nt)
          acc[mt][nt] = __builtin_amdgcn_mfma_f32_16x16x32_bf16(
              afr[mt], bfr[nt], acc[mt][nt], 0, 0, 0);
    }

    // epilogue 1: bias + gelu -> sT1. C/D: row=quad*4+r, col=lr (m89)
    #pragma unroll
    for (int nt = 0; nt < 6; ++nt) {
      const int n = n_base + nt * 16 + lr;
      const float bias = fb1[n];
      #pragma unroll
      for (int mt = 0; mt < 2; ++mt)
        #pragma unroll
        for (int r = 0; r < 4; ++r)
          sT1[mt * 16 + quad * 4 + r][n] = f2bf(gelu_f(acc[mt][nt][r] + bias));
    }
    // (c) sT1 ready
    __syncthreads();

    // ================= GEMM2: sT1[32x384] @ fw2T =================
    #pragma unroll
    for (int mt = 0; mt < 2; ++mt)
      #pragma unroll
      for (int nt = 0; nt < 6; ++nt)
        acc[mt][nt] = zero4;

    #pragma unroll 2
    for (int ks = 0; ks < 12; ++ks) {
      const int k0 = ks * 32 + quad * 8;
      bf16x8 afr[2];
      #pragma unroll
      for (int mt = 0; mt < 2; ++mt)
        afr[mt] = *(const bf16x8*)(&sT1[mt * 16 + lr][k0]);
      bf16x8 bfr[6];
      #pragma unroll
      for (int nt = 0; nt < 6; ++nt)
        bfr[nt] = *(const bf16x8*)(fw2T + (n_base + nt * 16 + lr) * Fz + k0);
      #pragma unroll
      for (int mt = 0; mt < 2; ++mt)
        #pragma unroll
        for (int nt = 0; nt < 6; ++nt)
          acc[mt][nt] = __builtin_amdgcn_mfma_f32_16x16x32_bf16(
              afr[mt], bfr[nt], acc[mt][nt], 0, 0, 0);
    }

    // epilogue 2: bias + gelu, multiply by h_V[b,k,:], accumulate per-column
    #pragma unroll
    for (int nt = 0; nt < 6; ++nt) {
      const int n = n_base + nt * 16 + lr;
      const float bias = fb2[n];
      float part = 0.f;
      #pragma unroll
      for (int mt = 0; mt < 2; ++mt) {
        const float* hv =
            hV + ((size_t)b * Lz + it * KT + mt * 16 + quad * 4) * Fz + n;
        #pragma unroll
        for (int r = 0; r < 4; ++r) {
          float w = gelu_f(acc[mt][nt][r] + bias);
          part += w * hv[(size_t)r * Fz];
        }
      }
      xc[nt] += part;
    }
  }

  // reduce xc across quads (rows) -> sXC
  #pragma unroll
  for (int nt = 0; nt < 6; ++nt) {
    float v = xc[nt];
    v += __shfl_xor(v, 16);
    v += __shfl_xor(v, 32);
    if (quad == 0) sXC[n_base + nt * 16 + lr] = v;
  }
  __syncthreads();

  // ---- head MLP (fp32, tiny) ----
  {
    int i = tid & 127;
    int half = tid >> 7;
    float a = 0.f;
    const int f0 = half * 192;
    for (int f = f0; f < f0 + 192; ++f) a += sXC[f] * hw1[f * Hz + i];
    sHp[half][i] = a;
  }
  __syncthreads();
  if (tid < Hz) sH1[tid] = gelu_f(sHp[0][tid] + sHp[1][tid] + hb1[tid]);
  __syncthreads();
  if (tid < 64) {
    float a = hb2[tid];
    for (int i = 0; i < Hz; ++i) a += sH1[i] * hw2[i * 64 + tid];
    sH2[tid] = gelu_f(a);
  }
  __syncthreads();
  if (wave == 0) {
    float v = sH2[lane] * hw3[lane];
    #pragma unroll
    for (int off = 32; off >= 1; off >>= 1) v += __shfl_xor(v, off);
    if (lane == 0) {
      float pred = v + hb3[0];
      atomicAdd(&accbuf[b], pred * mask[b * Lz + l]);
    }
  }
}

__global__ __launch_bounds__(64) void finalize_kernel(
    const float* __restrict__ mask, const float* __restrict__ accbuf,
    float* __restrict__ out)
{
  int b = blockIdx.x;
  int lane = threadIdx.x;
  float s = 0.f;
  for (int i = lane; i < Lz; i += 64) s += mask[b * Lz + i];
  #pragma unroll
  for (int off = 32; off >= 1; off >>= 1) s += __shfl_xor(s, off);
  if (lane == 0) {
    float vl = s < 1.0f ? 1.0f : s;
    out[b] = accbuf[b] / sqrtf(vl);
  }
}

extern "C" void kernel_launch(void* const* d_in, const int* in_sizes, int n_in,
                              void* d_out, int out_size, void* d_ws, size_t ws_size,
                              hipStream_t stream)
{
  const float* hV   = (const float*)d_in[0];
  const float* hE   = (const float*)d_in[1];
  const float* mask = (const float*)d_in[2];
  const float* fw1  = (const float*)d_in[3];
  const float* fb1  = (const float*)d_in[4];
  const float* fw2  = (const float*)d_in[5];
  const float* fb2  = (const float*)d_in[6];
  const float* hw1  = (const float*)d_in[7];
  const float* hb1  = (const float*)d_in[8];
  const float* hw2  = (const float*)d_in[9];
  const float* hb2  = (const float*)d_in[10];
  const float* hw3  = (const float*)d_in[11];
  const float* hb3  = (const float*)d_in[12];
  float* out = (float*)d_out;

  // ws layout: [0,64)=acc floats; [1024, +96KB)=fw1T bf16; then fw2T bf16.
  float* accbuf = (float*)d_ws;
  unsigned short* fw1T = (unsigned short*)((char*)d_ws + 1024);
  unsigned short* fw2T = fw1T + Hz * Fz;

  prep_kernel<<<576, 256, 0, stream>>>(fw1, fw2, fw1T, fw2T, accbuf);
  schnet_main<<<Bz * Lz, 256, 0, stream>>>(hV, hE, mask, fw1T, fb1, fw2T, fb2,
                                           hw1, hb1, hw2, hb2, hw3, hb3, accbuf);
  finalize_kernel<<<Bz, 64, 0, stream>>>(mask, accbuf, out);
}

// Round 3
// 1154.774 us; speedup vs baseline: 1.4589x; 1.1260x over previous
//
#include <hip/hip_runtime.h>
#include <hip/hip_bf16.h>

// StabilityPredictorSchnet: B=4, L=384, H=128, F=384
// One block per (b,l). 12 k-tiles of 32 edge rows, software-pipelined:
//   stage h_E tile -> LDS bf16 (register-prefetched)
//   GEMM1: sA[32x128] @ fw1 -> gelu -> sT1 (bf16 LDS)  [mfma 16x16x32 bf16]
//   GEMM2: sT1[32x384] @ fw2 -> gelu -> * h_V -> xc[]  (register accum)
// R2 lesson: acc[2][6]+bfr[6] blew the 128-VGPR budget -> 283 MB of scratch
// spills. Fix: split N into 2 passes of 3 tiles (acc[2][3], bfr[3]).
// R2 lesson: per-lane B-loads hit 16 different rows (uncoalesced). Fix:
// prep packs fw1/fw2 into MFMA fragment order -> 1KB/wave coalesced loads.

#define Bz 4
#define Lz 384
#define Hz 128
#define Fz 384
#define KT 32          // k-tile rows (edge rows per iteration)
#define NIT 12         // 384 / KT

typedef short bf16x8 __attribute__((ext_vector_type(8)));
typedef float f32x4 __attribute__((ext_vector_type(4)));

__device__ __forceinline__ unsigned short f2bf(float f) {
  unsigned int u = __float_as_uint(f);
  u += 0x7FFFu + ((u >> 16) & 1u);   // RNE bf16
  return (unsigned short)(u >> 16);
}

// gelu(x) = 0.5x(1+erf(x/sqrt2)); erf via A&S 7.1.26 (|err|<=1.5e-7), branch-free
__device__ __forceinline__ float gelu_f(float x) {
  const float a1 = 0.254829592f, a2 = -0.284496736f, a3 = 1.421413741f;
  const float a4 = -1.453152027f, a5 = 1.061405429f;
  float z = fabsf(x) * 0.7071067811865476f;
  float t = __builtin_amdgcn_rcpf(__builtin_fmaf(0.3275911f, z, 1.0f));
  float poly = t * (a1 + t * (a2 + t * (a3 + t * (a4 + t * a5))));
  float e = __builtin_fmaf(-poly, __expf(-z * z), 1.0f);
  return 0.5f * x * (1.0f + copysignf(e, x));
}

// ---- prep: zero accumulators; pack fw1/fw2 into MFMA B-fragment order ----
// fw1P[t][ks][lane][j] = fw1[ks*32+(lane>>4)*8+j][t*16+(lane&15)], t<24, ks<4
// fw2P[t][ks][lane][j] = fw2[ks*32+(lane>>4)*8+j][t*16+(lane&15)], t<24, ks<12
__global__ __launch_bounds__(256) void prep_kernel(
    const float* __restrict__ fw1, const float* __restrict__ fw2,
    unsigned short* __restrict__ fw1P, unsigned short* __restrict__ fw2P,
    float* __restrict__ accbuf)
{
  int e = blockIdx.x * 256 + threadIdx.x;
  if (e < 16) accbuf[e] = 0.0f;
  if (e < 24 * 4 * 64) {
    int lane = e & 63, r = e >> 6;
    int ks = r & 3, t = r >> 2;
    int n  = t * 16 + (lane & 15);
    int kb = ks * 32 + (lane >> 4) * 8;
    unsigned short o[8];
    #pragma unroll
    for (int j = 0; j < 8; ++j) o[j] = f2bf(fw1[(size_t)(kb + j) * Fz + n]);
    #pragma unroll
    for (int j = 0; j < 8; ++j) fw1P[(size_t)e * 8 + j] = o[j];
  }
  if (e < 24 * 12 * 64) {
    int lane = e & 63, r = e >> 6;
    int ks = r % 12, t = r / 12;
    int n  = t * 16 + (lane & 15);
    int kb = ks * 32 + (lane >> 4) * 8;
    unsigned short o[8];
    #pragma unroll
    for (int j = 0; j < 8; ++j) o[j] = f2bf(fw2[(size_t)(kb + j) * Fz + n]);
    #pragma unroll
    for (int j = 0; j < 8; ++j) fw2P[(size_t)e * 8 + j] = o[j];
  }
}

__global__ __launch_bounds__(256, 4) void schnet_main(
    const float* __restrict__ hV, const float* __restrict__ hE,
    const float* __restrict__ mask,
    const unsigned short* __restrict__ fw1P, const float* __restrict__ fb1,
    const unsigned short* __restrict__ fw2P, const float* __restrict__ fb2,
    const float* __restrict__ hw1, const float* __restrict__ hb1,
    const float* __restrict__ hw2, const float* __restrict__ hb2,
    const float* __restrict__ hw3, const float* __restrict__ hb3,
    float* __restrict__ accbuf)
{
  const int bl   = blockIdx.x;
  const int b    = bl / Lz;
  const int l    = bl - b * Lz;
  const int tid  = threadIdx.x;
  const int wave = tid >> 6;
  const int lane = tid & 63;
  const int lr   = lane & 15;   // 16-index (row for A, col for B/C)
  const int quad = lane >> 4;   // 0..3

  __shared__ unsigned short sA[KT][136];   // h_E tile, bf16      (8704 B)
  __shared__ unsigned short sT1[KT][392];  // gelu(hE@fw1) bf16   (25088 B)
  __shared__ float sXC[Fz];
  __shared__ float sHp[2][Hz];
  __shared__ float sH1[Hz];
  __shared__ float sH2[64];

  const float* hE_bl = hE + (size_t)bl * (Lz * Hz);
  // per-wave packed-weight bases (lane offset folded in)
  const unsigned short* w1p = fw1P + ((size_t)(wave * 6) * 4  * 64 + lane) * 8;
  const unsigned short* w2p = fw2P + ((size_t)(wave * 6) * 12 * 64 + lane) * 8;

  float xc[6] = {0.f, 0.f, 0.f, 0.f, 0.f, 0.f};
  const f32x4 zero4 = {0.f, 0.f, 0.f, 0.f};

  // prefetch tile 0 into registers (4 float4 per thread = one 32x128 tile)
  float4 pf[4];
  #pragma unroll
  for (int j = 0; j < 4; ++j)
    pf[j] = *(const float4*)(hE_bl + 4 * (tid + 256 * j));

  for (int it = 0; it < NIT; ++it) {
    // (a) prev iteration done reading sA / sT1
    __syncthreads();

    #pragma unroll
    for (int j = 0; j < 4; ++j) {
      int f = 4 * (tid + 256 * j);       // flat float idx in 32x128 tile
      int row = f >> 7, col = f & 127;
      short4 s;
      s.x = (short)f2bf(pf[j].x); s.y = (short)f2bf(pf[j].y);
      s.z = (short)f2bf(pf[j].z); s.w = (short)f2bf(pf[j].w);
      *(short4*)&sA[row][col] = s;
    }
    if (it + 1 < NIT) {
      const float* src = hE_bl + (size_t)(it + 1) * (KT * Hz);
      #pragma unroll
      for (int j = 0; j < 4; ++j)
        pf[j] = *(const float4*)(src + 4 * (tid + 256 * j));
    }
    // (b) sA ready
    __syncthreads();

    // ============ GEMM1: sA[32x128] @ fw1, two N-passes of 3 ============
    #pragma unroll
    for (int nh = 0; nh < 2; ++nh) {
      f32x4 acc[2][3];
      #pragma unroll
      for (int mt = 0; mt < 2; ++mt)
        #pragma unroll
        for (int i = 0; i < 3; ++i) acc[mt][i] = zero4;

      #pragma unroll
      for (int ks = 0; ks < 4; ++ks) {
        const int k0 = ks * 32 + quad * 8;
        bf16x8 afr[2];
        #pragma unroll
        for (int mt = 0; mt < 2; ++mt)
          afr[mt] = *(const bf16x8*)(&sA[mt * 16 + lr][k0]);
        bf16x8 bfr[3];
        #pragma unroll
        for (int i = 0; i < 3; ++i)
          bfr[i] = *(const bf16x8*)(w1p + ((nh * 3 + i) * 4 + ks) * 64 * 8);
        #pragma unroll
        for (int mt = 0; mt < 2; ++mt)
          #pragma unroll
          for (int i = 0; i < 3; ++i)
            acc[mt][i] = __builtin_amdgcn_mfma_f32_16x16x32_bf16(
                afr[mt], bfr[i], acc[mt][i], 0, 0, 0);
      }
      // epilogue 1: bias + gelu -> sT1. C/D: row=quad*4+r, col=lr (m89)
      #pragma unroll
      for (int i = 0; i < 3; ++i) {
        const int n = wave * 96 + (nh * 3 + i) * 16 + lr;
        const float bias = fb1[n];
        #pragma unroll
        for (int mt = 0; mt < 2; ++mt)
          #pragma unroll
          for (int r = 0; r < 4; ++r)
            sT1[mt * 16 + quad * 4 + r][n] =
                f2bf(gelu_f(acc[mt][i][r] + bias));
      }
    }
    // (c) sT1 ready
    __syncthreads();

    // ============ GEMM2: sT1[32x384] @ fw2, two N-passes of 3 ============
    #pragma unroll
    for (int nh = 0; nh < 2; ++nh) {
      f32x4 acc[2][3];
      #pragma unroll
      for (int mt = 0; mt < 2; ++mt)
        #pragma unroll
        for (int i = 0; i < 3; ++i) acc[mt][i] = zero4;

      #pragma unroll 2
      for (int ks = 0; ks < 12; ++ks) {
        const int k0 = ks * 32 + quad * 8;
        bf16x8 afr[2];
        #pragma unroll
        for (int mt = 0; mt < 2; ++mt)
          afr[mt] = *(const bf16x8*)(&sT1[mt * 16 + lr][k0]);
        bf16x8 bfr[3];
        #pragma unroll
        for (int i = 0; i < 3; ++i)
          bfr[i] = *(const bf16x8*)(w2p + ((nh * 3 + i) * 12 + ks) * 64 * 8);
        #pragma unroll
        for (int mt = 0; mt < 2; ++mt)
          #pragma unroll
          for (int i = 0; i < 3; ++i)
            acc[mt][i] = __builtin_amdgcn_mfma_f32_16x16x32_bf16(
                afr[mt], bfr[i], acc[mt][i], 0, 0, 0);
      }
      // epilogue 2: bias + gelu, multiply by h_V[b,k,:], accumulate
      #pragma unroll
      for (int i = 0; i < 3; ++i) {
        const int nl = nh * 3 + i;
        const int n  = wave * 96 + nl * 16 + lr;
        const float bias = fb2[i == 0 ? n : n];  // keep simple indexing
        float part = 0.f;
        #pragma unroll
        for (int mt = 0; mt < 2; ++mt) {
          const float* hv =
              hV + ((size_t)b * Lz + it * KT + mt * 16 + quad * 4) * Fz + n;
          #pragma unroll
          for (int r = 0; r < 4; ++r) {
            float w = gelu_f(acc[mt][i][r] + bias);
            part += w * hv[(size_t)r * Fz];
          }
        }
        xc[nl] += part;
      }
    }
  }

  // reduce xc across quads (rows) -> sXC
  #pragma unroll
  for (int nl = 0; nl < 6; ++nl) {
    float v = xc[nl];
    v += __shfl_xor(v, 16);
    v += __shfl_xor(v, 32);
    if (quad == 0) sXC[wave * 96 + nl * 16 + lr] = v;
  }
  __syncthreads();

  // ---- head MLP (fp32, tiny) ----
  {
    int i = tid & 127;
    int half = tid >> 7;
    float a = 0.f;
    const int f0 = half * 192;
    for (int f = f0; f < f0 + 192; ++f) a += sXC[f] * hw1[f * Hz + i];
    sHp[half][i] = a;
  }
  __syncthreads();
  if (tid < Hz) sH1[tid] = gelu_f(sHp[0][tid] + sHp[1][tid] + hb1[tid]);
  __syncthreads();
  if (tid < 64) {
    float a = hb2[tid];
    for (int i = 0; i < Hz; ++i) a += sH1[i] * hw2[i * 64 + tid];
    sH2[tid] = gelu_f(a);
  }
  __syncthreads();
  if (wave == 0) {
    float v = sH2[lane] * hw3[lane];
    #pragma unroll
    for (int off = 32; off >= 1; off >>= 1) v += __shfl_xor(v, off);
    if (lane == 0) {
      float pred = v + hb3[0];
      atomicAdd(&accbuf[b], pred * mask[b * Lz + l]);
    }
  }
}

__global__ __launch_bounds__(64) void finalize_kernel(
    const float* __restrict__ mask, const float* __restrict__ accbuf,
    float* __restrict__ out)
{
  int b = blockIdx.x;
  int lane = threadIdx.x;
  float s = 0.f;
  for (int i = lane; i < Lz; i += 64) s += mask[b * Lz + i];
  #pragma unroll
  for (int off = 32; off >= 1; off >>= 1) s += __shfl_xor(s, off);
  if (lane == 0) {
    float vl = s < 1.0f ? 1.0f : s;
    out[b] = accbuf[b] / sqrtf(vl);
  }
}

extern "C" void kernel_launch(void* const* d_in, const int* in_sizes, int n_in,
                              void* d_out, int out_size, void* d_ws, size_t ws_size,
                              hipStream_t stream)
{
  const float* hV   = (const float*)d_in[0];
  const float* hE   = (const float*)d_in[1];
  const float* mask = (const float*)d_in[2];
  const float* fw1  = (const float*)d_in[3];
  const float* fb1  = (const float*)d_in[4];
  const float* fw2  = (const float*)d_in[5];
  const float* fb2  = (const float*)d_in[6];
  const float* hw1  = (const float*)d_in[7];
  const float* hb1  = (const float*)d_in[8];
  const float* hw2  = (const float*)d_in[9];
  const float* hb2  = (const float*)d_in[10];
  const float* hw3  = (const float*)d_in[11];
  const float* hb3  = (const float*)d_in[12];
  float* out = (float*)d_out;

  // ws layout: [0,64)=acc floats; fw1P @1024 (96KB); fw2P after (288KB).
  float* accbuf = (float*)d_ws;
  unsigned short* fw1P = (unsigned short*)((char*)d_ws + 1024);
  unsigned short* fw2P = fw1P + 24 * 4 * 64 * 8;

  prep_kernel<<<72, 256, 0, stream>>>(fw1, fw2, fw1P, fw2P, accbuf);
  schnet_main<<<Bz * Lz, 256, 0, stream>>>(hV, hE, mask, fw1P, fb1, fw2P, fb2,
                                           hw1, hb1, hw2, hb2, hw3, hb3, accbuf);
  finalize_kernel<<<Bz, 64, 0, stream>>>(mask, accbuf, out);
}

// Round 4
// 1127.392 us; speedup vs baseline: 1.4943x; 1.0243x over previous
//
#include <hip/hip_runtime.h>
#include <hip/hip_bf16.h>

// StabilityPredictorSchnet: B=4, L=384, H=128, F=384
// One block per (b,l). 6 k-tiles of 64 edge rows:
//   DMA h_E fp32 tile -> LDS (global_load_lds w=16, staged in sT1 region)
//   repack -> sA bf16 (padded)
//   GEMM1: sA[64x128] @ fw1 -> gelu -> sT1 (bf16)   [mfma 16x16x32 bf16]
//   GEMM2: sT1[64x384] @ fw2 -> gelu -> * h_V -> xc (register accum)
// Head MLP + last-block finalize fused in.
// R3 lesson: register-held cross-GEMM prefetch -> spills (WRITE 421 MB,
// VGPR capped 64). Fix: global_load_lds (no VGPR roundtrip) + (256,2)
// bounds so acc[4][6] (96 AGPR) + frags fit the 256-reg tier (2 blk/CU,
// LDS-bound anyway at 71 KB).

#define Bz 4
#define Lz 384
#define Hz 128
#define Fz 384
#define KT 64          // k-tile rows (edge rows per iteration)
#define NIT 6          // 384 / KT

typedef short bf16x8 __attribute__((ext_vector_type(8)));
typedef float f32x4 __attribute__((ext_vector_type(4)));

__device__ __forceinline__ unsigned short f2bf(float f) {
  unsigned int u = __float_as_uint(f);
  u += 0x7FFFu + ((u >> 16) & 1u);   // RNE bf16
  return (unsigned short)(u >> 16);
}

// gelu(x) = 0.5x(1+erf(x/sqrt2)); erf via A&S 7.1.26 (|err|<=1.5e-7)
__device__ __forceinline__ float gelu_f(float x) {
  const float a1 = 0.254829592f, a2 = -0.284496736f, a3 = 1.421413741f;
  const float a4 = -1.453152027f, a5 = 1.061405429f;
  float z = fabsf(x) * 0.7071067811865476f;
  float t = __builtin_amdgcn_rcpf(__builtin_fmaf(0.3275911f, z, 1.0f));
  float poly = t * (a1 + t * (a2 + t * (a3 + t * (a4 + t * a5))));
  float e = __builtin_fmaf(-poly, __expf(-z * z), 1.0f);
  return 0.5f * x * (1.0f + copysignf(e, x));
}

// ---- prep: zero acc/counter; pack fw1/fw2 into MFMA B-fragment order ----
// fw1P flat: ((t*4+ks)*64+lane)*8+j  = bf(fw1[(ks*32+(lane>>4)*8+j)*F + t*16+(lane&15)])
// fw2P flat: ((t*12+ks)*64+lane)*8+j = bf(fw2[...same...])
__global__ __launch_bounds__(256) void prep_kernel(
    const float* __restrict__ fw1, const float* __restrict__ fw2,
    unsigned short* __restrict__ fw1P, unsigned short* __restrict__ fw2P,
    float* __restrict__ accbuf, int* __restrict__ ctr)
{
  int e = blockIdx.x * 256 + threadIdx.x;
  if (e < 16) accbuf[e] = 0.0f;
  if (e == 16) *ctr = 0;
  if (e < 24 * 4 * 64 * 8) {
    int j = e & 7, lf = (e >> 3) & 63, ks = (e >> 9) & 3, t = e >> 11;
    int n = t * 16 + (lf & 15);
    int k = ks * 32 + (lf >> 4) * 8 + j;
    fw1P[e] = f2bf(fw1[(size_t)k * Fz + n]);
  } else if (e < 24 * 4 * 64 * 8 + 24 * 12 * 64 * 8) {
    int o = e - 24 * 4 * 64 * 8;
    int j = o & 7, lf = (o >> 3) & 63, r = o >> 9;
    int ks = r % 12, t = r / 12;
    int n = t * 16 + (lf & 15);
    int k = ks * 32 + (lf >> 4) * 8 + j;
    fw2P[o] = f2bf(fw2[(size_t)k * Fz + n]);
  }
}

__global__ __launch_bounds__(256, 2) void schnet_main(
    const float* __restrict__ hV, const float* __restrict__ hE,
    const float* __restrict__ mask,
    const unsigned short* __restrict__ fw1P, const float* __restrict__ fb1,
    const unsigned short* __restrict__ fw2P, const float* __restrict__ fb2,
    const float* __restrict__ hw1, const float* __restrict__ hb1,
    const float* __restrict__ hw2, const float* __restrict__ hb2,
    const float* __restrict__ hw3, const float* __restrict__ hb3,
    float* __restrict__ accbuf, int* __restrict__ ctr,
    float* __restrict__ out)
{
  const int bl   = blockIdx.x;
  const int b    = bl / Lz;
  const int l    = bl - b * Lz;
  const int tid  = threadIdx.x;
  const int wave = tid >> 6;
  const int lane = tid & 63;
  const int lr   = lane & 15;   // 16-index (row for A, col for B/C)
  const int quad = lane >> 4;   // 0..3

  // sT1 region doubles as the fp32 staging buffer (32 KB <= 50 KB).
  __shared__ unsigned short sT1[KT][392];  // 50176 B
  __shared__ unsigned short sA[KT][136];   // 17408 B, padded bf16 tile
  __shared__ float sXC[Fz];
  __shared__ float sHp[2][Hz];
  __shared__ float sH1[Hz];
  __shared__ float sH2[64];
  __shared__ int   sLast;

  float* sStage = (float*)&sT1[0][0];

  const float* hE_bl = hE + (size_t)bl * (Lz * Hz);
  const unsigned short* w1base = fw1P + (size_t)lane * 8;
  const unsigned short* w2base = fw2P + (size_t)lane * 8;

  float xc[6] = {0.f, 0.f, 0.f, 0.f, 0.f, 0.f};
  const f32x4 zero4 = {0.f, 0.f, 0.f, 0.f};

  for (int it = 0; it < NIT; ++it) {
    // (a) prev iter done with sA (GEMM1) and sT1 (GEMM2)
    __syncthreads();

    // ---- DMA 64x128 fp32 tile -> sStage (wave-uniform base + lane*16) ----
    {
      const char* gt = (const char*)(hE_bl + (size_t)it * (KT * Hz));
      #pragma unroll
      for (int j = 0; j < 8; ++j) {
        int chunk = (j * 4 + wave) * 1024;      // bytes
        __builtin_amdgcn_global_load_lds(
            (const __attribute__((address_space(1))) void*)(gt + chunk + lane * 16),
            (__attribute__((address_space(3))) void*)((char*)sStage + chunk),
            16, 0, 0);
      }
    }
    // (b) DMA complete
    __syncthreads();

    // ---- repack fp32 stage -> bf16 sA (conflict-free both sides) ----
    #pragma unroll
    for (int s = 0; s < 8; ++s) {
      int f = 4 * tid + 1024 * s;
      float4 v = *(const float4*)(sStage + f);
      int row = f >> 7, col = f & 127;
      short4 o;
      o.x = (short)f2bf(v.x); o.y = (short)f2bf(v.y);
      o.z = (short)f2bf(v.z); o.w = (short)f2bf(v.w);
      *(short4*)&sA[row][col] = o;
    }
    // (c) sA ready; sStage region free for epi1 output
    __syncthreads();

    // ============ GEMM1: sA[64x128] @ fw1 (wave owns 96 cols) ============
    {
      f32x4 acc[4][6];
      #pragma unroll
      for (int mt = 0; mt < 4; ++mt)
        #pragma unroll
        for (int nt = 0; nt < 6; ++nt) acc[mt][nt] = zero4;

      #pragma unroll
      for (int ks = 0; ks < 4; ++ks) {
        const int k0 = ks * 32 + quad * 8;
        bf16x8 afr[4];
        #pragma unroll
        for (int mt = 0; mt < 4; ++mt)
          afr[mt] = *(const bf16x8*)(&sA[mt * 16 + lr][k0]);
        bf16x8 bfr[6];
        #pragma unroll
        for (int nt = 0; nt < 6; ++nt)
          bfr[nt] = *(const bf16x8*)(w1base +
                        (size_t)(((wave * 6 + nt) * 4 + ks) * 64) * 8);
        #pragma unroll
        for (int mt = 0; mt < 4; ++mt)
          #pragma unroll
          for (int nt = 0; nt < 6; ++nt)
            acc[mt][nt] = __builtin_amdgcn_mfma_f32_16x16x32_bf16(
                afr[mt], bfr[nt], acc[mt][nt], 0, 0, 0);
      }
      // epi1: bias+gelu -> sT1. C/D: row=quad*4+r, col=lr (m89)
      #pragma unroll
      for (int nt = 0; nt < 6; ++nt) {
        const int n = wave * 96 + nt * 16 + lr;
        const float bias = fb1[n];
        #pragma unroll
        for (int mt = 0; mt < 4; ++mt)
          #pragma unroll
          for (int r = 0; r < 4; ++r)
            sT1[mt * 16 + quad * 4 + r][n] =
                f2bf(gelu_f(acc[mt][nt][r] + bias));
      }
    }
    // (d) sT1 ready
    __syncthreads();

    // ============ GEMM2: sT1[64x384] @ fw2 ============
    {
      f32x4 acc[4][6];
      #pragma unroll
      for (int mt = 0; mt < 4; ++mt)
        #pragma unroll
        for (int nt = 0; nt < 6; ++nt) acc[mt][nt] = zero4;

      #pragma unroll 4
      for (int ks = 0; ks < 12; ++ks) {
        const int k0 = ks * 32 + quad * 8;
        bf16x8 afr[4];
        #pragma unroll
        for (int mt = 0; mt < 4; ++mt)
          afr[mt] = *(const bf16x8*)(&sT1[mt * 16 + lr][k0]);
        bf16x8 bfr[6];
        #pragma unroll
        for (int nt = 0; nt < 6; ++nt)
          bfr[nt] = *(const bf16x8*)(w2base +
                        (size_t)(((wave * 6 + nt) * 12 + ks) * 64) * 8);
        #pragma unroll
        for (int mt = 0; mt < 4; ++mt)
          #pragma unroll
          for (int nt = 0; nt < 6; ++nt)
            acc[mt][nt] = __builtin_amdgcn_mfma_f32_16x16x32_bf16(
                afr[mt], bfr[nt], acc[mt][nt], 0, 0, 0);
      }
      // epi2: bias+gelu, * h_V[b,k,n], accumulate per column
      #pragma unroll
      for (int nt = 0; nt < 6; ++nt) {
        const int n = wave * 96 + nt * 16 + lr;
        const float bias = fb2[n];
        float part = 0.f;
        #pragma unroll
        for (int mt = 0; mt < 4; ++mt) {
          const float* hv =
              hV + ((size_t)b * Lz + it * KT + mt * 16 + quad * 4) * Fz + n;
          #pragma unroll
          for (int r = 0; r < 4; ++r) {
            float w = gelu_f(acc[mt][nt][r] + bias);
            part += w * hv[(size_t)r * Fz];
          }
        }
        xc[nt] += part;
      }
    }
  }

  // reduce xc across quads -> sXC
  #pragma unroll
  for (int nt = 0; nt < 6; ++nt) {
    float v = xc[nt];
    v += __shfl_xor(v, 16);
    v += __shfl_xor(v, 32);
    if (quad == 0) sXC[wave * 96 + nt * 16 + lr] = v;
  }
  __syncthreads();

  // ---- head MLP (fp32, tiny) ----
  {
    int i = tid & 127;
    int half = tid >> 7;
    float a = 0.f;
    const int f0 = half * 192;
    for (int f = f0; f < f0 + 192; ++f) a += sXC[f] * hw1[f * Hz + i];
    sHp[half][i] = a;
  }
  __syncthreads();
  if (tid < Hz) sH1[tid] = gelu_f(sHp[0][tid] + sHp[1][tid] + hb1[tid]);
  __syncthreads();
  if (tid < 64) {
    float a = hb2[tid];
    for (int i = 0; i < Hz; ++i) a += sH1[i] * hw2[i * 64 + tid];
    sH2[tid] = gelu_f(a);
  }
  __syncthreads();
  if (wave == 0) {
    float v = sH2[lane] * hw3[lane];
    #pragma unroll
    for (int off = 32; off >= 1; off >>= 1) v += __shfl_xor(v, off);
    if (lane == 0) {
      float pred = v + hb3[0];
      atomicAdd(&accbuf[b], pred * mask[b * Lz + l]);
      __threadfence();
      sLast = (atomicAdd(ctr, 1) == (Bz * Lz - 1));
    }
  }
  __syncthreads();

  // ---- last block: finalize all 4 batches ----
  if (sLast && wave < Bz) {
    float s = 0.f;
    #pragma unroll
    for (int k = 0; k < Lz / 64; ++k) s += mask[wave * Lz + k * 64 + lane];
    #pragma unroll
    for (int off = 32; off >= 1; off >>= 1) s += __shfl_xor(s, off);
    if (lane == 0) {
      float vl = s < 1.0f ? 1.0f : s;
      float a = atomicAdd(&accbuf[wave], 0.0f);   // coherent read
      out[wave] = a / sqrtf(vl);
    }
  }
}

extern "C" void kernel_launch(void* const* d_in, const int* in_sizes, int n_in,
                              void* d_out, int out_size, void* d_ws, size_t ws_size,
                              hipStream_t stream)
{
  const float* hV   = (const float*)d_in[0];
  const float* hE   = (const float*)d_in[1];
  const float* mask = (const float*)d_in[2];
  const float* fw1  = (const float*)d_in[3];
  const float* fb1  = (const float*)d_in[4];
  const float* fw2  = (const float*)d_in[5];
  const float* fb2  = (const float*)d_in[6];
  const float* hw1  = (const float*)d_in[7];
  const float* hb1  = (const float*)d_in[8];
  const float* hw2  = (const float*)d_in[9];
  const float* hb2  = (const float*)d_in[10];
  const float* hw3  = (const float*)d_in[11];
  const float* hb3  = (const float*)d_in[12];
  float* out = (float*)d_out;

  // ws: [0,64) accbuf; [64,68) ctr; fw1P @1024 (96 KB); fw2P after (288 KB)
  float* accbuf = (float*)d_ws;
  int*   ctr    = (int*)((char*)d_ws + 64);
  unsigned short* fw1P = (unsigned short*)((char*)d_ws + 1024);
  unsigned short* fw2P = fw1P + 24 * 4 * 64 * 8;

  prep_kernel<<<768, 256, 0, stream>>>(fw1, fw2, fw1P, fw2P, accbuf, ctr);
  schnet_main<<<Bz * Lz, 256, 0, stream>>>(hV, hE, mask, fw1P, fb1, fw2P, fb2,
                                           hw1, hb1, hw2, hb2, hw3, hb3,
                                           accbuf, ctr, out);
}